// Round 2
// baseline (333.218 us; speedup 1.0000x reference)
//
#include <hip/hip_runtime.h>

#define N_NODES 100000
#define N_EDGES 1600000
#define CAP 48      // deg~Poisson(16); P(deg>=48)*N ~ 3e-6 -> no drops (rounds 4-8 absmax confirm)
#define NBUCK 256   // dst-range buckets
#define NPB 391     // nodes per bucket = ceil(100000/256)
#define SCAP 8192   // bucket segment capacity (mean 6250, sigma 79 -> +24 sigma)
#define EPB 4096    // edges per bin_edges block
#define NSPLIT 4    // dim splits: 16 dims * 100k nodes * 2B = 3.2 MB slice < 4 MB per-XCD L2
#define BPS ((N_NODES * 4 + 255) / 256)   // blocks per split = 1563 (4 lanes/node)

typedef unsigned int uint;
typedef unsigned short ushort;

__device__ __forceinline__ void fma4(float4& c, float s, const float4& w) {
    c.x += s * w.x; c.y += s * w.y; c.z += s * w.z; c.w += s * w.w;
}

__device__ __forceinline__ ushort bf16r(float f) {   // fp32 -> bf16 RNE
    union { float f; uint u; } v; v.f = f;
    return (ushort)((v.u + 0x7fffu + ((v.u >> 16) & 1u)) >> 16);
}

// ---------------- fp32 GEMM block: H[128 rows][64 cols], K=128 ----------------
// Value-typed thread state (round-2 lesson: address-cast locals -> scratch spill).
struct alignas(16) GemmSmem {
    float Xs[128][36];   // stride 36: 16B-aligned rows
    float Ws[32][64];
};

// OutT=float: node-major [n][64] (weight collapse).
// OutT=ushort: bf16, DIM-SPLIT layout [NSPLIT][N_NODES][16 dims] so each
// aggregation split gathers from a 3.2 MB L2-resident slice.
template <typename OutT>
__device__ __forceinline__ void gemm64_block(GemmSmem& sm, int bid,
                                             const float* __restrict__ X,
                                             const float* __restrict__ W,
                                             OutT* __restrict__ H, int n) {
    const int tid  = threadIdx.x;
    const int row0 = bid * 128;
    const int rg   = tid >> 4;          // 0..15: rows 8*rg .. 8*rg+7
    const int cg   = tid & 15;          // col group: cg*4

    float4 acc0[8];
#pragma unroll
    for (int r = 0; r < 8; r++) acc0[r] = make_float4(0.f, 0.f, 0.f, 0.f);

    const int lr = tid >> 1;
    const int lh = tid & 1;
    int grow = row0 + lr; if (grow > n - 1) grow = n - 1;   // clamp tail reads
    const float* gx_base = X + (size_t)grow * 128 + lh * 16;

    for (int k0 = 0; k0 < 128; k0 += 32) {
        const float* gx = gx_base + k0;
#pragma unroll
        for (int i = 0; i < 4; i++)
            *(float4*)&sm.Xs[lr][lh * 16 + 4 * i] = *(const float4*)(gx + 4 * i);
        const float4* gw = (const float4*)(W + (size_t)k0 * 64);
        float4* sw = (float4*)&sm.Ws[0][0];
#pragma unroll
        for (int i = 0; i < 2; i++) sw[tid + 256 * i] = gw[tid + 256 * i];
        __syncthreads();

#pragma unroll
        for (int kk = 0; kk < 32; kk += 4) {
            float4 w00 = *(const float4*)&sm.Ws[kk + 0][cg * 4];
            float4 w01 = *(const float4*)&sm.Ws[kk + 1][cg * 4];
            float4 w02 = *(const float4*)&sm.Ws[kk + 2][cg * 4];
            float4 w03 = *(const float4*)&sm.Ws[kk + 3][cg * 4];
#pragma unroll
            for (int r = 0; r < 8; r++) {
                float4 a = *(const float4*)&sm.Xs[rg * 8 + r][kk];
                fma4(acc0[r], a.x, w00);
                fma4(acc0[r], a.y, w01);
                fma4(acc0[r], a.z, w02);
                fma4(acc0[r], a.w, w03);
            }
        }
        __syncthreads();
    }

#pragma unroll
    for (int r = 0; r < 8; r++) {
        int row = row0 + rg * 8 + r;
        if (row < n) {
            if constexpr (sizeof(OutT) == 2) {   // bf16, dim-split layout
                uint2 o;
                o.x = (uint)bf16r(acc0[r].x) | ((uint)bf16r(acc0[r].y) << 16);
                o.y = (uint)bf16r(acc0[r].z) | ((uint)bf16r(acc0[r].w) << 16);
                const int s = cg >> 2;          // dim split 0..3
                const int q = cg & 3;           // uint2 slot within slice row
                *(uint2*)((uint*)H + ((size_t)s * N_NODES + row) * 8 + q * 2) = o;
            } else {
                *(float4*)&H[(size_t)row * 64 + cg * 4] = *(float4*)&acc0[r];
            }
        }
    }
}

// ---------------- Pass A + weight collapse (fused) ----------------
// Blocks 0..390: LDS-histogram edge binning into NBUCK dst-range segments.
// Block 391: Wc = W1 @ (W2 @ W3) hides under the binning blocks.
union BinWcSmem {
    struct { int ecnt[NBUCK]; int base[NBUCK]; int lcur[NBUCK]; } b;
    GemmSmem g;
};

__global__ void __launch_bounds__(256) bin_wc(const int* __restrict__ src,
                                              const int* __restrict__ dst,
                                              int* __restrict__ gcur,
                                              uint2* __restrict__ seg, int E,
                                              const float* __restrict__ W1,
                                              const float* __restrict__ W2,
                                              const float* __restrict__ W3,
                                              float* __restrict__ W23,
                                              float* __restrict__ Wc) {
    __shared__ BinWcSmem sh;
    if (blockIdx.x == gridDim.x - 1) {      // weight-collapse block
        gemm64_block<float>(sh.g, 0, W2, W3, W23, 128);
        __syncthreads();                     // W23 global writes visible in-block
        gemm64_block<float>(sh.g, 0, W1, W23, Wc, 128);
        return;
    }
    const int t = threadIdx.x;
    sh.b.ecnt[t] = 0; sh.b.lcur[t] = 0;      // t spans exactly NBUCK
    __syncthreads();
    const int e0 = blockIdx.x * EPB;
    // phase 1: LDS histogram
#pragma unroll
    for (int k = 0; k < EPB / 256; k++) {
        int i = e0 + k * 256 + t;
        if (i < E) atomicAdd(&sh.b.ecnt[dst[i] / NPB], 1);
    }
    __syncthreads();
    // phase 2: one global reserving atomic per non-empty bucket
    sh.b.base[t] = (sh.b.ecnt[t] > 0) ? atomicAdd(&gcur[t], sh.b.ecnt[t]) : 0;
    __syncthreads();
    // phase 3: write this block's edges contiguously into each bucket segment
#pragma unroll
    for (int k = 0; k < EPB / 256; k++) {
        int i = e0 + k * 256 + t;
        if (i < E) {
            int d = dst[i];
            int b = d / NPB;
            int s = sh.b.base[b] + atomicAdd(&sh.b.lcur[b], 1);
            if (s < SCAP) seg[(size_t)b * SCAP + s] = make_uint2((uint)src[i], (uint)d);
        }
    }
}

// ---------------- Pass B + main GEMM (fused, heterogeneous blocks) ----------------
// CSR build (latency/scatter-bound, 256 blocks) overlapped with Y = X @ Wc
// (VALU-bound, 782 blocks); independent -> sum becomes max.
union CsrGemmSmem {
    int lc[NPB];
    GemmSmem g;
};

__global__ void __launch_bounds__(256, 3) csr_gemm(const int* __restrict__ gcur,
                                                   const uint2* __restrict__ seg,
                                                   int* __restrict__ col,
                                                   int* __restrict__ cnt,
                                                   const float* __restrict__ X,
                                                   const float* __restrict__ Wc,
                                                   ushort* __restrict__ Y, int n) {
    __shared__ CsrGemmSmem sh;
    if (blockIdx.x < NBUCK) {
        const int b = blockIdx.x;
        const int t = threadIdx.x;
        for (int i = t; i < NPB; i += 256) sh.lc[i] = 0;
        __syncthreads();
        int m = gcur[b]; if (m > SCAP) m = SCAP;
        const uint2* sg = seg + (size_t)b * SCAP;
        const int node0 = b * NPB;
        for (int i = t; i < m; i += 256) {
            uint2 e = sg[i];
            int d = (int)e.y;
            int slot = atomicAdd(&sh.lc[d - node0], 1);
            if (slot < CAP) col[(size_t)d * CAP + slot] = (int)e.x;
        }
        __syncthreads();
        for (int i = t; i < NPB; i += 256) {
            int node = node0 + i;
            if (node < n) cnt[node] = (sh.lc[i] > CAP) ? CAP : sh.lc[i];
        }
    } else {
        gemm64_block<ushort>(sh.g, blockIdx.x - NBUCK, X, Wc, Y, n);
    }
}

// ---------------- Aggregation, dim-split bf16 table ----------------
// Table layout [NSPLIT][N][16 dims bf16]; each split's 3.2 MB slice is
// L2-resident per XCD, so the deg~16 reuse is served from L2 instead of
// thrashing to MALL (round-1 counters: 85 MB FETCH/pass = L2-miss bound).
// 4 lanes per node; lane owns a uint2 (4 dims) -> 32 B contiguous gather
// per edge per split. Splits are block-contiguous so they run roughly
// sequentially; accumulation tree per dim unchanged.
__device__ __forceinline__ float2 bf2f(uint u) {
    union { uint u; float f; } a, b;
    a.u = u << 16; b.u = u & 0xffff0000u;
    return make_float2(a.f, b.f);
}

template <bool FINAL>
__global__ void __launch_bounds__(256) agg64s(const uint2* __restrict__ T_in,
                                              const int* __restrict__ cnt,
                                              const int* __restrict__ col,
                                              void* __restrict__ T_out, int n) {
    const int b = blockIdx.x;
    const int s = b / BPS;                    // dim split 0..3
    const int idx = (b - s * BPS) * 256 + threadIdx.x;
    const int node = idx >> 2;
    const int lane = idx & 3;                 // owns local dims [4*lane, 4*lane+4)
    if (node >= n) return;
    int m = cnt[node]; if (m > CAP) m = CAP;
    const int* cb = col + (size_t)node * CAP;
    const uint2* tb = T_in + ((size_t)s * n) * 4 + lane;   // slice base + lane slot
    float4 acc = make_float4(0.f, 0.f, 0.f, 0.f);
    int j = 0;
    for (; j + 8 <= m; j += 8) {
        int s0 = cb[j],     s1 = cb[j + 1], s2 = cb[j + 2], s3 = cb[j + 3];
        int s4 = cb[j + 4], s5 = cb[j + 5], s6 = cb[j + 6], s7 = cb[j + 7];
        uint2 u0 = tb[(size_t)s0 * 4];
        uint2 u1 = tb[(size_t)s1 * 4];
        uint2 u2 = tb[(size_t)s2 * 4];
        uint2 u3 = tb[(size_t)s3 * 4];
        uint2 u4 = tb[(size_t)s4 * 4];
        uint2 u5 = tb[(size_t)s5 * 4];
        uint2 u6 = tb[(size_t)s6 * 4];
        uint2 u7 = tb[(size_t)s7 * 4];
        float2 a0 = bf2f(u0.x), a1 = bf2f(u1.x), a2 = bf2f(u2.x), a3 = bf2f(u3.x);
        float2 a4 = bf2f(u4.x), a5 = bf2f(u5.x), a6 = bf2f(u6.x), a7 = bf2f(u7.x);
        float2 b0 = bf2f(u0.y), b1 = bf2f(u1.y), b2 = bf2f(u2.y), b3 = bf2f(u3.y);
        float2 b4 = bf2f(u4.y), b5 = bf2f(u5.y), b6 = bf2f(u6.y), b7 = bf2f(u7.y);
        acc.x += ((a0.x + a1.x) + (a2.x + a3.x)) + ((a4.x + a5.x) + (a6.x + a7.x));
        acc.y += ((a0.y + a1.y) + (a2.y + a3.y)) + ((a4.y + a5.y) + (a6.y + a7.y));
        acc.z += ((b0.x + b1.x) + (b2.x + b3.x)) + ((b4.x + b5.x) + (b6.x + b7.x));
        acc.w += ((b0.y + b1.y) + (b2.y + b3.y)) + ((b4.y + b5.y) + (b6.y + b7.y));
    }
    for (; j + 4 <= m; j += 4) {
        int s0 = cb[j], s1 = cb[j + 1], s2 = cb[j + 2], s3 = cb[j + 3];
        uint2 u0 = tb[(size_t)s0 * 4];
        uint2 u1 = tb[(size_t)s1 * 4];
        uint2 u2 = tb[(size_t)s2 * 4];
        uint2 u3 = tb[(size_t)s3 * 4];
        float2 a0 = bf2f(u0.x), a1 = bf2f(u1.x), a2 = bf2f(u2.x), a3 = bf2f(u3.x);
        float2 b0 = bf2f(u0.y), b1 = bf2f(u1.y), b2 = bf2f(u2.y), b3 = bf2f(u3.y);
        acc.x += (a0.x + a1.x) + (a2.x + a3.x);
        acc.y += (a0.y + a1.y) + (a2.y + a3.y);
        acc.z += (b0.x + b1.x) + (b2.x + b3.x);
        acc.w += (b0.y + b1.y) + (b2.y + b3.y);
    }
    for (; j < m; j++) {
        uint2 u = tb[(size_t)cb[j] * 4];
        float2 a = bf2f(u.x), bb = bf2f(u.y);
        acc.x += a.x; acc.y += a.y; acc.z += bb.x; acc.w += bb.y;
    }
    if (FINAL) {
        // out is node-major fp32 [n][64]; this split owns dims s*16 + lane*4 ..
        ((float4*)T_out)[(size_t)node * 16 + s * 4 + lane] = acc;
    } else {
        uint2 o;
        o.x = (uint)bf16r(acc.x) | ((uint)bf16r(acc.y) << 16);
        o.y = (uint)bf16r(acc.z) | ((uint)bf16r(acc.w) << 16);
        ((uint2*)T_out)[((size_t)s * n + node) * 4 + lane] = o;
    }
}

// ---------------- launch ----------------
// ALGEBRAIC COLLAPSE: out = A(A(A X W1)W2)W3 = A^3 . X . (W1 W2 W3)
// -> one 128->64 GEMM + three dim-split aggregations + binned CSR build.
// This round: dim-split node tables ([4][N][16] bf16) so each agg split
// gathers from an L2-resident 3.2 MB slice instead of thrashing 12.8 MB
// through 4 MB per-XCD L2 (round-1: FETCH 85 MB/pass -> predicted ~35-45).

static inline size_t align_up(size_t x, size_t a) { return (x + a - 1) & ~(a - 1); }

extern "C" void kernel_launch(void* const* d_in, const int* in_sizes, int n_in,
                              void* d_out, int out_size, void* d_ws, size_t ws_size,
                              hipStream_t stream) {
    const float* x  = (const float*)d_in[0];
    const int*   ei = (const int*)d_in[1];   // [2, E]
    const float* W1 = (const float*)d_in[2];
    const float* W2 = (const float*)d_in[3];
    const float* W3 = (const float*)d_in[4];
    float* out = (float*)d_out;

    const int N = N_NODES;
    const int E = N_EDGES;
    const int* src = ei;
    const int* dst = ei + E;

    // workspace carve-up (~63 MB)
    char* p = (char*)d_ws;
    int*    gcur = (int*)p;   p += align_up((size_t)NBUCK * 4, 256);
    int*    cnt  = (int*)p;   p += align_up((size_t)N * 4, 256);
    uint2*  seg  = (uint2*)p; p += align_up((size_t)NBUCK * SCAP * 8, 256);  // 16.8 MB
    int*    col  = (int*)p;   p += align_up((size_t)N * CAP * 4, 256);       // 19.2 MB
    float*  W23  = (float*)p; p += align_up((size_t)128 * 64 * 4, 256);
    float*  Wc   = (float*)p; p += align_up((size_t)128 * 64 * 4, 256);
    ushort* Y    = (ushort*)p; p += align_up((size_t)N * 64 * 2, 256);  // bf16 table [4][N][16]
    ushort* Za   = (ushort*)p; p += align_up((size_t)N * 64 * 2, 256);  // bf16 ping-pong

    hipMemsetAsync(gcur, 0, (size_t)NBUCK * 4, stream);

    // ---- Pass A: bin edges; block 391 computes Wc = W1 @ (W2 @ W3) ----
    const int bin_blocks = (E + EPB - 1) / EPB;          // 391
    bin_wc<<<bin_blocks + 1, 256, 0, stream>>>(src, dst, gcur, seg, E,
                                               W1, W2, W3, W23, Wc);

    // ---- Pass B (blocks 0..255) overlapped with Y = X @ Wc (blocks 256..) ----
    const int gemm_blocks = (N + 127) / 128;             // 782
    csr_gemm<<<NBUCK + gemm_blocks, 256, 0, stream>>>(gcur, seg, col, cnt,
                                                      x, Wc, Y, N);

    // ---- out = A^3 Y (dim-split passes) ----
    const int agg_blocks = NSPLIT * BPS;                 // 6252
    agg64s<false><<<agg_blocks, 256, 0, stream>>>((const uint2*)Y,  cnt, col, Za, N);
    agg64s<false><<<agg_blocks, 256, 0, stream>>>((const uint2*)Za, cnt, col, Y,  N);
    agg64s<true ><<<agg_blocks, 256, 0, stream>>>((const uint2*)Y,  cnt, col, out, N);
}

// Round 3
// 291.815 us; speedup vs baseline: 1.1419x; 1.1419x over previous
//
#include <hip/hip_runtime.h>

#define N_NODES 100000
#define N_EDGES 1600000
#define CAP 48      // deg~Poisson(16); P(deg>=48)*N ~ 3e-6 -> no drops
#define NBUCK 256   // dst-range buckets
#define NPB 391     // nodes per bucket = ceil(100000/256)
#define SCAP 8192   // bucket segment capacity (mean 6250, sigma 79 -> +24 sigma)
#define EPB 4096    // edges per bin block
#define NBIN ((N_EDGES + EPB - 1) / EPB)     // 391
#define NGEMM ((N_NODES + 127) / 128)        // 782

typedef unsigned int uint;
typedef unsigned short ushort;

__device__ __forceinline__ void fma4(float4& c, float s, const float4& w) {
    c.x += s * w.x; c.y += s * w.y; c.z += s * w.z; c.w += s * w.w;
}

__device__ __forceinline__ ushort bf16r(float f) {   // fp32 -> bf16 RNE
    union { float f; uint u; } v; v.f = f;
    return (ushort)((v.u + 0x7fffu + ((v.u >> 16) & 1u)) >> 16);
}

// ---------------- fp32 GEMM block: H[128 rows][64 cols], K=128 ----------------
// Value-typed thread state (address-cast locals -> scratch spill lesson).
struct alignas(16) GemmSmem {
    float Xs[128][36];   // stride 36: 16B-aligned rows
    float Ws[32][64];
};

// OutT=float: fp32 out. OutT=ushort: bf16 out. Node-major [row][64].
template <typename OutT>
__device__ __forceinline__ void gemm64_block(GemmSmem& sm, int bid,
                                             const float* __restrict__ X,
                                             const float* __restrict__ W,
                                             OutT* __restrict__ H, int n) {
    const int tid  = threadIdx.x;
    const int row0 = bid * 128;
    const int rg   = tid >> 4;          // 0..15: rows 8*rg .. 8*rg+7
    const int cg   = tid & 15;          // col group: cg*4

    float4 acc0[8];
#pragma unroll
    for (int r = 0; r < 8; r++) acc0[r] = make_float4(0.f, 0.f, 0.f, 0.f);

    const int lr = tid >> 1;
    const int lh = tid & 1;
    int grow = row0 + lr; if (grow > n - 1) grow = n - 1;   // clamp tail reads
    const float* gx_base = X + (size_t)grow * 128 + lh * 16;

    for (int k0 = 0; k0 < 128; k0 += 32) {
        const float* gx = gx_base + k0;
#pragma unroll
        for (int i = 0; i < 4; i++)
            *(float4*)&sm.Xs[lr][lh * 16 + 4 * i] = *(const float4*)(gx + 4 * i);
        const float4* gw = (const float4*)(W + (size_t)k0 * 64);
        float4* sw = (float4*)&sm.Ws[0][0];
#pragma unroll
        for (int i = 0; i < 2; i++) sw[tid + 256 * i] = gw[tid + 256 * i];
        __syncthreads();

#pragma unroll
        for (int kk = 0; kk < 32; kk += 4) {
            float4 w00 = *(const float4*)&sm.Ws[kk + 0][cg * 4];
            float4 w01 = *(const float4*)&sm.Ws[kk + 1][cg * 4];
            float4 w02 = *(const float4*)&sm.Ws[kk + 2][cg * 4];
            float4 w03 = *(const float4*)&sm.Ws[kk + 3][cg * 4];
#pragma unroll
            for (int r = 0; r < 8; r++) {
                float4 a = *(const float4*)&sm.Xs[rg * 8 + r][kk];
                fma4(acc0[r], a.x, w00);
                fma4(acc0[r], a.y, w01);
                fma4(acc0[r], a.z, w02);
                fma4(acc0[r], a.w, w03);
            }
        }
        __syncthreads();
    }

#pragma unroll
    for (int r = 0; r < 8; r++) {
        int row = row0 + rg * 8 + r;
        if (row < n) {
            if constexpr (sizeof(OutT) == 2) {   // bf16 epilogue, node-major
                ushort4 o0 = make_ushort4(bf16r(acc0[r].x), bf16r(acc0[r].y),
                                          bf16r(acc0[r].z), bf16r(acc0[r].w));
                *(ushort4*)&H[(size_t)row * 64 + cg * 4] = o0;
            } else {
                *(float4*)&H[(size_t)row * 64 + cg * 4] = *(float4*)&acc0[r];
            }
        }
    }
}

// ---------------- K1: weight collapse + edge binning + main GEMM ----------------
// Block 0: Wc = W1 @ (W2 @ W3), then release flag (device scope).
// Blocks 1..NBIN: LDS-histogram edge binning into NBUCK dst-range segments.
// Blocks NBIN+1..: Y = X @ Wc tiles; spin on flag (~10 us) then compute,
// co-running with the memory/atomic-bound bin blocks on the same CUs.
// Residency: 1174 blocks, LDS 26.6 KB -> 6 blocks/CU -> 1536 slots >= 1174,
// so every block is resident and the spin cannot deadlock.
union FusedASmem {
    struct { int ecnt[NBUCK]; int base[NBUCK]; int lcur[NBUCK]; } b;
    GemmSmem g;
};

__global__ void __launch_bounds__(256, 3) fused_a(const int* __restrict__ src,
                                                  const int* __restrict__ dst,
                                                  int* __restrict__ gcur,
                                                  uint2* __restrict__ seg, int E,
                                                  const float* __restrict__ W1,
                                                  const float* __restrict__ W2,
                                                  const float* __restrict__ W3,
                                                  float* __restrict__ W23,
                                                  float* __restrict__ Wc,
                                                  int* __restrict__ wcflag,
                                                  const float* __restrict__ X,
                                                  ushort* __restrict__ Y, int n) {
    __shared__ FusedASmem sh;
    const int bx = blockIdx.x;
    if (bx == 0) {                           // ---- weight collapse ----
        gemm64_block<float>(sh.g, 0, W2, W3, W23, 128);
        __syncthreads();                     // W23 writes drained (round-0/1 proven)
        gemm64_block<float>(sh.g, 0, W1, W23, Wc, 128);
        __syncthreads();                     // all lanes' Wc stores issued
        if (threadIdx.x == 0) {
            __threadfence();                 // Wc visible device-wide
            __hip_atomic_store(wcflag, 1, __ATOMIC_RELEASE, __HIP_MEMORY_SCOPE_AGENT);
        }
        return;
    }
    if (bx <= NBIN) {                        // ---- edge binning ----
        const int t = threadIdx.x;
        sh.b.ecnt[t] = 0; sh.b.lcur[t] = 0;  // t spans exactly NBUCK
        __syncthreads();
        const int e0 = (bx - 1) * EPB;
        // phase 1: LDS histogram
#pragma unroll
        for (int k = 0; k < EPB / 256; k++) {
            int i = e0 + k * 256 + t;
            if (i < E) atomicAdd(&sh.b.ecnt[dst[i] / NPB], 1);
        }
        __syncthreads();
        // phase 2: one global reserving atomic per non-empty bucket
        sh.b.base[t] = (sh.b.ecnt[t] > 0) ? atomicAdd(&gcur[t], sh.b.ecnt[t]) : 0;
        __syncthreads();
        // phase 3: write this block's edges contiguously into each segment
#pragma unroll
        for (int k = 0; k < EPB / 256; k++) {
            int i = e0 + k * 256 + t;
            if (i < E) {
                int d = dst[i];
                int b = d / NPB;
                int s = sh.b.base[b] + atomicAdd(&sh.b.lcur[b], 1);
                if (s < SCAP) seg[(size_t)b * SCAP + s] = make_uint2((uint)src[i], (uint)d);
            }
        }
        return;
    }
    // ---- main GEMM tile: wait for Wc then compute ----
    if (threadIdx.x == 0) {
        while (!__hip_atomic_load(wcflag, __ATOMIC_ACQUIRE, __HIP_MEMORY_SCOPE_AGENT))
            __builtin_amdgcn_s_sleep(16);
    }
    __syncthreads();
    gemm64_block<ushort>(sh.g, bx - 1 - NBIN, X, Wc, Y, n);
}

// ---------------- K2: per-bucket CSR build ----------------
// Slot assignment in LDS, scatter into a 75 KB L2-local window per block;
// cnt written coalesced (doubles as the cnt memset).
__global__ void __launch_bounds__(1024) build_csr(const int* __restrict__ gcur,
                                                  const uint2* __restrict__ seg,
                                                  int* __restrict__ col,
                                                  int* __restrict__ cnt, int n) {
    __shared__ int lc[NPB];
    const int b = blockIdx.x;
    const int t = threadIdx.x;
    for (int i = t; i < NPB; i += 1024) lc[i] = 0;
    __syncthreads();
    int m = gcur[b]; if (m > SCAP) m = SCAP;
    const uint2* sg = seg + (size_t)b * SCAP;
    const int node0 = b * NPB;
    for (int i = t; i < m; i += 1024) {
        uint2 e = sg[i];
        int d = (int)e.y;
        int slot = atomicAdd(&lc[d - node0], 1);
        if (slot < CAP) col[(size_t)d * CAP + slot] = (int)e.x;
    }
    __syncthreads();
    for (int i = t; i < NPB; i += 1024) {
        int node = node0 + i;
        if (node < n) cnt[node] = (lc[i] > CAP) ? CAP : lc[i];
    }
}

// ---------------- Aggregation, width 64, bf16 table [N][64] ----------------
// 16 lanes per node; lane owns a uint2 (4 dims) -> one coalesced 128 B
// (exactly one cacheline) gather per edge. Round-2 lesson: do NOT dim-split;
// 32 B slice rows cause 4x line-granularity amplification on L2 misses.
__device__ __forceinline__ float2 bf2f(uint u) {
    union { uint u; float f; } a, b;
    a.u = u << 16; b.u = u & 0xffff0000u;
    return make_float2(a.f, b.f);
}

template <bool FINAL>
__global__ void __launch_bounds__(256) agg64(const uint2* __restrict__ T_in,
                                             const int* __restrict__ cnt,
                                             const int* __restrict__ col,
                                             void* __restrict__ T_out, int n) {
    int gid  = blockIdx.x * blockDim.x + threadIdx.x;
    int node = gid >> 4;
    int lane = gid & 15;                 // owns dims [4*lane, 4*lane+4)
    if (node >= n) return;
    int m = cnt[node]; if (m > CAP) m = CAP;
    const int* cb = col + (size_t)node * CAP;
    float4 acc = make_float4(0.f, 0.f, 0.f, 0.f);
    int j = 0;
    for (; j + 8 <= m; j += 8) {
        int s0 = cb[j],     s1 = cb[j + 1], s2 = cb[j + 2], s3 = cb[j + 3];
        int s4 = cb[j + 4], s5 = cb[j + 5], s6 = cb[j + 6], s7 = cb[j + 7];
        uint2 u0 = T_in[(size_t)s0 * 16 + lane];
        uint2 u1 = T_in[(size_t)s1 * 16 + lane];
        uint2 u2 = T_in[(size_t)s2 * 16 + lane];
        uint2 u3 = T_in[(size_t)s3 * 16 + lane];
        uint2 u4 = T_in[(size_t)s4 * 16 + lane];
        uint2 u5 = T_in[(size_t)s5 * 16 + lane];
        uint2 u6 = T_in[(size_t)s6 * 16 + lane];
        uint2 u7 = T_in[(size_t)s7 * 16 + lane];
        float2 a0 = bf2f(u0.x), a1 = bf2f(u1.x), a2 = bf2f(u2.x), a3 = bf2f(u3.x);
        float2 a4 = bf2f(u4.x), a5 = bf2f(u5.x), a6 = bf2f(u6.x), a7 = bf2f(u7.x);
        float2 b0 = bf2f(u0.y), b1 = bf2f(u1.y), b2 = bf2f(u2.y), b3 = bf2f(u3.y);
        float2 b4 = bf2f(u4.y), b5 = bf2f(u5.y), b6 = bf2f(u6.y), b7 = bf2f(u7.y);
        acc.x += ((a0.x + a1.x) + (a2.x + a3.x)) + ((a4.x + a5.x) + (a6.x + a7.x));
        acc.y += ((a0.y + a1.y) + (a2.y + a3.y)) + ((a4.y + a5.y) + (a6.y + a7.y));
        acc.z += ((b0.x + b1.x) + (b2.x + b3.x)) + ((b4.x + b5.x) + (b6.x + b7.x));
        acc.w += ((b0.y + b1.y) + (b2.y + b3.y)) + ((b4.y + b5.y) + (b6.y + b7.y));
    }
    for (; j + 4 <= m; j += 4) {
        int s0 = cb[j], s1 = cb[j + 1], s2 = cb[j + 2], s3 = cb[j + 3];
        uint2 u0 = T_in[(size_t)s0 * 16 + lane];
        uint2 u1 = T_in[(size_t)s1 * 16 + lane];
        uint2 u2 = T_in[(size_t)s2 * 16 + lane];
        uint2 u3 = T_in[(size_t)s3 * 16 + lane];
        float2 a0 = bf2f(u0.x), a1 = bf2f(u1.x), a2 = bf2f(u2.x), a3 = bf2f(u3.x);
        float2 b0 = bf2f(u0.y), b1 = bf2f(u1.y), b2 = bf2f(u2.y), b3 = bf2f(u3.y);
        acc.x += (a0.x + a1.x) + (a2.x + a3.x);
        acc.y += (a0.y + a1.y) + (a2.y + a3.y);
        acc.z += (b0.x + b1.x) + (b2.x + b3.x);
        acc.w += (b0.y + b1.y) + (b2.y + b3.y);
    }
    for (; j < m; j++) {
        uint2 u = T_in[(size_t)cb[j] * 16 + lane];
        float2 a = bf2f(u.x), b = bf2f(u.y);
        acc.x += a.x; acc.y += a.y; acc.z += b.x; acc.w += b.y;
    }
    if (FINAL) {
        ((float4*)T_out)[(size_t)node * 16 + lane] = acc;
    } else {
        uint2 o;
        o.x = (uint)bf16r(acc.x) | ((uint)bf16r(acc.y) << 16);
        o.y = (uint)bf16r(acc.z) | ((uint)bf16r(acc.w) << 16);
        ((uint2*)T_out)[(size_t)node * 16 + lane] = o;
    }
}

// ---------------- launch ----------------
// ALGEBRAIC COLLAPSE: out = A(A(A X W1)W2)W3 = A^3 . X . (W1 W2 W3)
// Pipeline: [K1: wc + bin + GEMM co-run via Wc spin-flag][K2: CSR][3x agg].
// Fixed 41 us harness poison-fill is in the timed region (budget model r2).

static inline size_t align_up(size_t x, size_t a) { return (x + a - 1) & ~(a - 1); }

extern "C" void kernel_launch(void* const* d_in, const int* in_sizes, int n_in,
                              void* d_out, int out_size, void* d_ws, size_t ws_size,
                              hipStream_t stream) {
    const float* x  = (const float*)d_in[0];
    const int*   ei = (const int*)d_in[1];   // [2, E]
    const float* W1 = (const float*)d_in[2];
    const float* W2 = (const float*)d_in[3];
    const float* W3 = (const float*)d_in[4];
    float* out = (float*)d_out;

    const int N = N_NODES;
    const int E = N_EDGES;
    const int* src = ei;
    const int* dst = ei + E;

    // workspace carve-up (~63 MB)
    char* p = (char*)d_ws;
    int*    gcur = (int*)p;   p += align_up((size_t)(NBUCK + 64) * 4, 256);
    int*    wcflag = gcur + NBUCK;           // zeroed together with gcur
    int*    cnt  = (int*)p;   p += align_up((size_t)N * 4, 256);
    uint2*  seg  = (uint2*)p; p += align_up((size_t)NBUCK * SCAP * 8, 256);  // 16.8 MB
    int*    col  = (int*)p;   p += align_up((size_t)N * CAP * 4, 256);       // 19.2 MB
    float*  W23  = (float*)p; p += align_up((size_t)128 * 64 * 4, 256);
    float*  Wc   = (float*)p; p += align_up((size_t)128 * 64 * 4, 256);
    ushort* Y    = (ushort*)p; p += align_up((size_t)N * 64 * 2, 256);  // bf16 node table
    ushort* Za   = (ushort*)p; p += align_up((size_t)N * 64 * 2, 256);  // bf16 ping-pong

    hipMemsetAsync(gcur, 0, (size_t)(NBUCK + 64) * 4, stream);

    // ---- K1: block 0 = Wc collapse; 1..NBIN = bin; rest = GEMM (spin on Wc) ----
    fused_a<<<1 + NBIN + NGEMM, 256, 0, stream>>>(src, dst, gcur, seg, E,
                                                  W1, W2, W3, W23, Wc, wcflag,
                                                  x, Y, N);

    // ---- K2: per-bucket CSR build ----
    build_csr<<<NBUCK, 1024, 0, stream>>>(gcur, seg, col, cnt, N);

    // ---- out = A^3 Y ----
    const int agg_blocks = (N * 16 + 255) / 256;   // 6250
    agg64<false><<<agg_blocks, 256, 0, stream>>>((const uint2*)Y,  cnt, col, Za, N);
    agg64<false><<<agg_blocks, 256, 0, stream>>>((const uint2*)Za, cnt, col, Y,  N);
    agg64<true ><<<agg_blocks, 256, 0, stream>>>((const uint2*)Y,  cnt, col, out, N);
}

// Round 4
// 254.726 us; speedup vs baseline: 1.3081x; 1.1456x over previous
//
#include <hip/hip_runtime.h>

#define N_NODES 100000
#define N_EDGES 1600000
#define CAP 48      // deg~Poisson(16); P(deg>=48)*N ~ 3e-6 -> no drops
#define NBUCK 256   // dst-range buckets
#define NPB 391     // nodes per bucket = ceil(100000/256)
#define SCAP 8192   // bucket segment capacity (mean 6250, sigma 79 -> +24 sigma)
#define EPB 4096    // edges per bin block
#define NBIN ((N_EDGES + EPB - 1) / EPB)     // 391

typedef unsigned int uint;
typedef unsigned short ushort;

__device__ __forceinline__ void fma4(float4& c, float s, const float4& w) {
    c.x += s * w.x; c.y += s * w.y; c.z += s * w.z; c.w += s * w.w;
}

__device__ __forceinline__ ushort bf16r(float f) {   // fp32 -> bf16 RNE
    union { float f; uint u; } v; v.f = f;
    return (ushort)((v.u + 0x7fffu + ((v.u >> 16) & 1u)) >> 16);
}

// ---------------- fp32 GEMM block: H[128 rows][64 cols], K=128 ----------------
// Value-typed thread state (address-cast locals -> scratch spill lesson).
struct alignas(16) GemmSmem {
    float Xs[128][36];   // stride 36: 16B-aligned rows
    float Ws[32][64];
};

template <typename OutT>
__device__ __forceinline__ void gemm64_block(GemmSmem& sm, int bid,
                                             const float* __restrict__ X,
                                             const float* __restrict__ W,
                                             OutT* __restrict__ H, int n) {
    const int tid  = threadIdx.x;
    const int row0 = bid * 128;
    const int rg   = tid >> 4;          // 0..15: rows 8*rg .. 8*rg+7
    const int cg   = tid & 15;          // col group: cg*4

    float4 acc0[8];
#pragma unroll
    for (int r = 0; r < 8; r++) acc0[r] = make_float4(0.f, 0.f, 0.f, 0.f);

    const int lr = tid >> 1;
    const int lh = tid & 1;
    int grow = row0 + lr; if (grow > n - 1) grow = n - 1;   // clamp tail reads
    const float* gx_base = X + (size_t)grow * 128 + lh * 16;

    for (int k0 = 0; k0 < 128; k0 += 32) {
        const float* gx = gx_base + k0;
#pragma unroll
        for (int i = 0; i < 4; i++)
            *(float4*)&sm.Xs[lr][lh * 16 + 4 * i] = *(const float4*)(gx + 4 * i);
        const float4* gw = (const float4*)(W + (size_t)k0 * 64);
        float4* sw = (float4*)&sm.Ws[0][0];
#pragma unroll
        for (int i = 0; i < 2; i++) sw[tid + 256 * i] = gw[tid + 256 * i];
        __syncthreads();

#pragma unroll
        for (int kk = 0; kk < 32; kk += 4) {
            float4 w00 = *(const float4*)&sm.Ws[kk + 0][cg * 4];
            float4 w01 = *(const float4*)&sm.Ws[kk + 1][cg * 4];
            float4 w02 = *(const float4*)&sm.Ws[kk + 2][cg * 4];
            float4 w03 = *(const float4*)&sm.Ws[kk + 3][cg * 4];
#pragma unroll
            for (int r = 0; r < 8; r++) {
                float4 a = *(const float4*)&sm.Xs[rg * 8 + r][kk];
                fma4(acc0[r], a.x, w00);
                fma4(acc0[r], a.y, w01);
                fma4(acc0[r], a.z, w02);
                fma4(acc0[r], a.w, w03);
            }
        }
        __syncthreads();
    }

#pragma unroll
    for (int r = 0; r < 8; r++) {
        int row = row0 + rg * 8 + r;
        if (row < n) {
            if constexpr (sizeof(OutT) == 2) {   // bf16 epilogue, node-major
                ushort4 o0 = make_ushort4(bf16r(acc0[r].x), bf16r(acc0[r].y),
                                          bf16r(acc0[r].z), bf16r(acc0[r].w));
                *(ushort4*)&H[(size_t)row * 64 + cg * 4] = o0;
            } else {
                *(float4*)&H[(size_t)row * 64 + cg * 4] = *(float4*)&acc0[r];
            }
        }
    }
}

// ---------------- Pass A + weight collapse (fused) ----------------
// Blocks 0..NBIN-1: LDS-histogram edge binning into NBUCK dst-range segments.
// Block NBIN: Wc = W1 @ (W2 @ W3) hides under the binning blocks.
// Round-3 lesson: do NOT co-run the main GEMM here — bin's LDS-atomic storm
// and the GEMM's ds_reads contend for the per-CU LDS pipe (3x stretch).
union BinWcSmem {
    struct { int ecnt[NBUCK]; int base[NBUCK]; int lcur[NBUCK]; } b;
    GemmSmem g;
};

__global__ void __launch_bounds__(256) bin_wc(const int* __restrict__ src,
                                              const int* __restrict__ dst,
                                              int* __restrict__ gcur,
                                              uint2* __restrict__ seg, int E,
                                              const float* __restrict__ W1,
                                              const float* __restrict__ W2,
                                              const float* __restrict__ W3,
                                              float* __restrict__ W23,
                                              float* __restrict__ Wc) {
    __shared__ BinWcSmem sh;
    if (blockIdx.x == gridDim.x - 1) {      // weight-collapse block
        gemm64_block<float>(sh.g, 0, W2, W3, W23, 128);
        __syncthreads();                     // W23 global writes visible in-block
        gemm64_block<float>(sh.g, 0, W1, W23, Wc, 128);
        return;
    }
    const int t = threadIdx.x;
    sh.b.ecnt[t] = 0; sh.b.lcur[t] = 0;      // t spans exactly NBUCK
    __syncthreads();
    const int e0 = blockIdx.x * EPB;
    // phase 1: LDS histogram
#pragma unroll
    for (int k = 0; k < EPB / 256; k++) {
        int i = e0 + k * 256 + t;
        if (i < E) atomicAdd(&sh.b.ecnt[dst[i] / NPB], 1);
    }
    __syncthreads();
    // phase 2: one global reserving atomic per non-empty bucket
    sh.b.base[t] = (sh.b.ecnt[t] > 0) ? atomicAdd(&gcur[t], sh.b.ecnt[t]) : 0;
    __syncthreads();
    // phase 3: write this block's edges contiguously into each bucket segment
#pragma unroll
    for (int k = 0; k < EPB / 256; k++) {
        int i = e0 + k * 256 + t;
        if (i < E) {
            int d = dst[i];
            int b = d / NPB;
            int s = sh.b.base[b] + atomicAdd(&sh.b.lcur[b], 1);
            if (s < SCAP) seg[(size_t)b * SCAP + s] = make_uint2((uint)src[i], (uint)d);
        }
    }
}

// ---------------- Pass B + main GEMM (fused, heterogeneous blocks) ----------------
// CSR build (global-scatter/latency-bound, light LDS) overlapped with
// Y = X @ Wc (VALU/LDS-bound) — this pairing is pipe-disjoint (round-1: 43 us).
union CsrGemmSmem {
    int lc[NPB];
    GemmSmem g;
};

__global__ void __launch_bounds__(256, 3) csr_gemm(const int* __restrict__ gcur,
                                                   const uint2* __restrict__ seg,
                                                   int* __restrict__ col,
                                                   int* __restrict__ cnt,
                                                   const float* __restrict__ X,
                                                   const float* __restrict__ Wc,
                                                   ushort* __restrict__ Y, int n) {
    __shared__ CsrGemmSmem sh;
    if (blockIdx.x < NBUCK) {
        const int b = blockIdx.x;
        const int t = threadIdx.x;
        for (int i = t; i < NPB; i += 256) sh.lc[i] = 0;
        __syncthreads();
        int m = gcur[b]; if (m > SCAP) m = SCAP;
        const uint2* sg = seg + (size_t)b * SCAP;
        const int node0 = b * NPB;
        for (int i = t; i < m; i += 256) {
            uint2 e = sg[i];
            int d = (int)e.y;
            int slot = atomicAdd(&sh.lc[d - node0], 1);
            if (slot < CAP) col[(size_t)d * CAP + slot] = (int)e.x;
        }
        __syncthreads();
        for (int i = t; i < NPB; i += 256) {
            int node = node0 + i;
            if (node < n) cnt[node] = (sh.lc[i] > CAP) ? CAP : sh.lc[i];
        }
    } else {
        gemm64_block<ushort>(sh.g, blockIdx.x - NBUCK, X, Wc, Y, n);
    }
}

// ---------------- Aggregation, width 64, bf16 table [N][64] ----------------
// 8 lanes per node; lane owns a uint4 (8 dims, 16 B) -> one coalesced 128 B
// (exactly one cacheline) gather per edge, 2x bytes-in-flight per wave vs
// the uint2 variant (round-0 counters: latency/MLP-bound, not BW-bound).
// col indices loaded as int4 (rows are 192 B, 16B-aligned). Per-dim
// accumulation tree unchanged -> bitwise-identical output.
__device__ __forceinline__ float2 bf2f(uint u) {
    union { uint u; float f; } a, b;
    a.u = u << 16; b.u = u & 0xffff0000u;
    return make_float2(a.f, b.f);
}

template <bool FINAL>
__global__ void __launch_bounds__(256) agg64(const uint4* __restrict__ T_in,
                                             const int* __restrict__ cnt,
                                             const int* __restrict__ col,
                                             void* __restrict__ T_out, int n) {
    int gid  = blockIdx.x * blockDim.x + threadIdx.x;
    int node = gid >> 3;
    int lane = gid & 7;                  // owns dims [8*lane, 8*lane+8)
    if (node >= n) return;
    int m = cnt[node]; if (m > CAP) m = CAP;
    const int* cb = col + (size_t)node * CAP;
    const uint4* tb = T_in + lane;
    float4 accA = make_float4(0.f, 0.f, 0.f, 0.f);
    float4 accB = make_float4(0.f, 0.f, 0.f, 0.f);
    int j = 0;
    for (; j + 8 <= m; j += 8) {
        int4 c0 = *(const int4*)&cb[j];
        int4 c1 = *(const int4*)&cb[j + 4];
        uint4 u0 = tb[(size_t)c0.x * 8];
        uint4 u1 = tb[(size_t)c0.y * 8];
        uint4 u2 = tb[(size_t)c0.z * 8];
        uint4 u3 = tb[(size_t)c0.w * 8];
        uint4 u4 = tb[(size_t)c1.x * 8];
        uint4 u5 = tb[(size_t)c1.y * 8];
        uint4 u6 = tb[(size_t)c1.z * 8];
        uint4 u7 = tb[(size_t)c1.w * 8];
        float2 p0 = bf2f(u0.x), p1 = bf2f(u1.x), p2 = bf2f(u2.x), p3 = bf2f(u3.x);
        float2 p4 = bf2f(u4.x), p5 = bf2f(u5.x), p6 = bf2f(u6.x), p7 = bf2f(u7.x);
        accA.x += ((p0.x + p1.x) + (p2.x + p3.x)) + ((p4.x + p5.x) + (p6.x + p7.x));
        accA.y += ((p0.y + p1.y) + (p2.y + p3.y)) + ((p4.y + p5.y) + (p6.y + p7.y));
        float2 q0 = bf2f(u0.y), q1 = bf2f(u1.y), q2 = bf2f(u2.y), q3 = bf2f(u3.y);
        float2 q4 = bf2f(u4.y), q5 = bf2f(u5.y), q6 = bf2f(u6.y), q7 = bf2f(u7.y);
        accA.z += ((q0.x + q1.x) + (q2.x + q3.x)) + ((q4.x + q5.x) + (q6.x + q7.x));
        accA.w += ((q0.y + q1.y) + (q2.y + q3.y)) + ((q4.y + q5.y) + (q6.y + q7.y));
        float2 r0 = bf2f(u0.z), r1 = bf2f(u1.z), r2 = bf2f(u2.z), r3 = bf2f(u3.z);
        float2 r4 = bf2f(u4.z), r5 = bf2f(u5.z), r6 = bf2f(u6.z), r7 = bf2f(u7.z);
        accB.x += ((r0.x + r1.x) + (r2.x + r3.x)) + ((r4.x + r5.x) + (r6.x + r7.x));
        accB.y += ((r0.y + r1.y) + (r2.y + r3.y)) + ((r4.y + r5.y) + (r6.y + r7.y));
        float2 s0 = bf2f(u0.w), s1 = bf2f(u1.w), s2 = bf2f(u2.w), s3 = bf2f(u3.w);
        float2 s4 = bf2f(u4.w), s5 = bf2f(u5.w), s6 = bf2f(u6.w), s7 = bf2f(u7.w);
        accB.z += ((s0.x + s1.x) + (s2.x + s3.x)) + ((s4.x + s5.x) + (s6.x + s7.x));
        accB.w += ((s0.y + s1.y) + (s2.y + s3.y)) + ((s4.y + s5.y) + (s6.y + s7.y));
    }
    for (; j + 4 <= m; j += 4) {
        int4 c0 = *(const int4*)&cb[j];
        uint4 u0 = tb[(size_t)c0.x * 8];
        uint4 u1 = tb[(size_t)c0.y * 8];
        uint4 u2 = tb[(size_t)c0.z * 8];
        uint4 u3 = tb[(size_t)c0.w * 8];
        float2 p0 = bf2f(u0.x), p1 = bf2f(u1.x), p2 = bf2f(u2.x), p3 = bf2f(u3.x);
        accA.x += (p0.x + p1.x) + (p2.x + p3.x);
        accA.y += (p0.y + p1.y) + (p2.y + p3.y);
        float2 q0 = bf2f(u0.y), q1 = bf2f(u1.y), q2 = bf2f(u2.y), q3 = bf2f(u3.y);
        accA.z += (q0.x + q1.x) + (q2.x + q3.x);
        accA.w += (q0.y + q1.y) + (q2.y + q3.y);
        float2 r0 = bf2f(u0.z), r1 = bf2f(u1.z), r2 = bf2f(u2.z), r3 = bf2f(u3.z);
        accB.x += (r0.x + r1.x) + (r2.x + r3.x);
        accB.y += (r0.y + r1.y) + (r2.y + r3.y);
        float2 s0 = bf2f(u0.w), s1 = bf2f(u1.w), s2 = bf2f(u2.w), s3 = bf2f(u3.w);
        accB.z += (s0.x + s1.x) + (s2.x + s3.x);
        accB.w += (s0.y + s1.y) + (s2.y + s3.y);
    }
    for (; j < m; j++) {
        uint4 u = tb[(size_t)cb[j] * 8];
        float2 p = bf2f(u.x), q = bf2f(u.y), r = bf2f(u.z), s = bf2f(u.w);
        accA.x += p.x; accA.y += p.y; accA.z += q.x; accA.w += q.y;
        accB.x += r.x; accB.y += r.y; accB.z += s.x; accB.w += s.y;
    }
    if (FINAL) {
        // out fp32 [n][64]; lane owns dims 8*lane..8*lane+7 -> two float4s
        ((float4*)T_out)[(size_t)node * 16 + lane * 2]     = accA;
        ((float4*)T_out)[(size_t)node * 16 + lane * 2 + 1] = accB;
    } else {
        uint4 o;
        o.x = (uint)bf16r(accA.x) | ((uint)bf16r(accA.y) << 16);
        o.y = (uint)bf16r(accA.z) | ((uint)bf16r(accA.w) << 16);
        o.z = (uint)bf16r(accB.x) | ((uint)bf16r(accB.y) << 16);
        o.w = (uint)bf16r(accB.z) | ((uint)bf16r(accB.w) << 16);
        ((uint4*)T_out)[(size_t)node * 8 + lane] = o;
    }
}

// ---------------- launch ----------------
// ALGEBRAIC COLLAPSE: out = A(A(A X W1)W2)W3 = A^3 . X . (W1 W2 W3)
// Pipeline (round-1 proven): [bin + wc][CSR || GEMM][agg x3].
// Round-3 lesson: keep GEMM off the bin kernel (LDS-pipe contention).

static inline size_t align_up(size_t x, size_t a) { return (x + a - 1) & ~(a - 1); }

extern "C" void kernel_launch(void* const* d_in, const int* in_sizes, int n_in,
                              void* d_out, int out_size, void* d_ws, size_t ws_size,
                              hipStream_t stream) {
    const float* x  = (const float*)d_in[0];
    const int*   ei = (const int*)d_in[1];   // [2, E]
    const float* W1 = (const float*)d_in[2];
    const float* W2 = (const float*)d_in[3];
    const float* W3 = (const float*)d_in[4];
    float* out = (float*)d_out;

    const int N = N_NODES;
    const int E = N_EDGES;
    const int* src = ei;
    const int* dst = ei + E;

    // workspace carve-up (~63 MB)
    char* p = (char*)d_ws;
    int*    gcur = (int*)p;   p += align_up((size_t)NBUCK * 4, 256);
    int*    cnt  = (int*)p;   p += align_up((size_t)N * 4, 256);
    uint2*  seg  = (uint2*)p; p += align_up((size_t)NBUCK * SCAP * 8, 256);  // 16.8 MB
    int*    col  = (int*)p;   p += align_up((size_t)N * CAP * 4, 256);       // 19.2 MB
    float*  W23  = (float*)p; p += align_up((size_t)128 * 64 * 4, 256);
    float*  Wc   = (float*)p; p += align_up((size_t)128 * 64 * 4, 256);
    ushort* Y    = (ushort*)p; p += align_up((size_t)N * 64 * 2, 256);  // bf16 node table
    ushort* Za   = (ushort*)p; p += align_up((size_t)N * 64 * 2, 256);  // bf16 ping-pong

    hipMemsetAsync(gcur, 0, (size_t)NBUCK * 4, stream);

    // ---- Pass A: bin edges; last block computes Wc = W1 @ (W2 @ W3) ----
    bin_wc<<<NBIN + 1, 256, 0, stream>>>(src, dst, gcur, seg, E,
                                         W1, W2, W3, W23, Wc);

    // ---- Pass B (blocks 0..255) overlapped with Y = X @ Wc (blocks 256..) ----
    const int gemm_blocks = (N + 127) / 128;             // 782
    csr_gemm<<<NBUCK + gemm_blocks, 256, 0, stream>>>(gcur, seg, col, cnt,
                                                      x, Wc, Y, N);

    // ---- out = A^3 Y ----
    const int agg_blocks = (N * 8 + 255) / 256;          // 3125
    agg64<false><<<agg_blocks, 256, 0, stream>>>((const uint4*)Y,  cnt, col, Za, N);
    agg64<false><<<agg_blocks, 256, 0, stream>>>((const uint4*)Za, cnt, col, Y,  N);
    agg64<true ><<<agg_blocks, 256, 0, stream>>>((const uint4*)Y,  cnt, col, out, N);
}